// Round 2
// baseline (326.593 us; speedup 1.0000x reference)
//
#include <hip/hip_runtime.h>

// B=4, H=8, S=1024, D=512, D_K=64. Inputs fp32 (mask int32); outputs (out, bias) fp32.
// Internal compute: bf16 MFMA (tolerance is ~2% of global absmax; bf16 chain err << that).

using bf16x8 = __attribute__((ext_vector_type(8))) __bf16;
using floatx4 = __attribute__((ext_vector_type(4))) float;

__device__ __forceinline__ unsigned short f2bf(float f) {
  union { float f; unsigned int i; } x; x.f = f;
  unsigned int i = x.i;
  return (unsigned short)((i + 0x7FFFu + ((i >> 16) & 1u)) >> 16);
}
__device__ __forceinline__ uint4 pack8(floatx4 a, floatx4 b) {
  union { uint4 u; unsigned short s[8]; } r;
#pragma unroll
  for (int j = 0; j < 4; ++j) { r.s[j] = f2bf(a[j]); r.s[4 + j] = f2bf(b[j]); }
  return r.u;
}

// ---------------------------------------------------------------------------
// Kernel 0: pack mask int32 [B,S,S] -> bit mask [B*S, S/32] words
// ---------------------------------------------------------------------------
__global__ __launch_bounds__(256) void pack_mask_kernel(const int* __restrict__ mask,
                                                        unsigned int* __restrict__ bits) {
  int tid = blockIdx.x * 256 + threadIdx.x;
  unsigned long long bm = __ballot(mask[tid] != 0);
  int lane = threadIdx.x & 63;
  if (lane == 0) bits[tid >> 5] = (unsigned int)bm;
  else if (lane == 32) bits[tid >> 5] = (unsigned int)(bm >> 32);
}

// ---------------------------------------------------------------------------
// NT GEMM: out[m,n] = sum_k A[m,k]*Bm[n,k] + bias[n]. M=4096,N=512,K=512.
// MODE 1: A fp32 (value), out bf16 in vT layout [(b*512+n)][1024] at col m&1023.
// MODE 0: A bf16 (xbuf),  out fp32 row-major [M,N] (final projection).
// B operand (weights) always fp32, converted to bf16 during staging.
// 64x64 tile, 4 waves, BK=64, XOR-swizzled LDS (16B chunks).
// ---------------------------------------------------------------------------
template <int MODE>
__global__ __launch_bounds__(256) void gemm_nt_kernel(const void* __restrict__ Av,
                                                      const float* __restrict__ Bm,
                                                      const float* __restrict__ bias,
                                                      void* __restrict__ outv,
                                                      int M, int N, int K) {
  __shared__ unsigned short As[64 * 64];
  __shared__ unsigned short Bs[64 * 64];
  int t = threadIdx.x;
  int m0 = blockIdx.x * 64, n0 = blockIdx.y * 64;
  int lr = t >> 2;          // staging row 0..63
  int c0 = (t & 3) * 2;     // staging chunk pair (chunks of 8 elems = one b128)
  int wave = t >> 6, l = t & 63, lm = l & 15, quad = l >> 4;
  floatx4 acc[4] = {{0,0,0,0},{0,0,0,0},{0,0,0,0},{0,0,0,0}};

  const float* brow = Bm + (size_t)(n0 + lr) * K + c0 * 8;

  for (int kk = 0; kk < K; kk += 64) {
    uint4 a0, a1;
    if (MODE == 1) {
      const float* arow = (const float*)Av + (size_t)(m0 + lr) * K + c0 * 8;
      floatx4 f0 = *(const floatx4*)(arow + kk);
      floatx4 f1 = *(const floatx4*)(arow + kk + 4);
      floatx4 f2 = *(const floatx4*)(arow + kk + 8);
      floatx4 f3 = *(const floatx4*)(arow + kk + 12);
      a0 = pack8(f0, f1); a1 = pack8(f2, f3);
    } else {
      const unsigned short* arow = (const unsigned short*)Av + (size_t)(m0 + lr) * K + c0 * 8;
      a0 = *(const uint4*)(arow + kk);
      a1 = *(const uint4*)(arow + kk + 8);
    }
    floatx4 g0 = *(const floatx4*)(brow + kk);
    floatx4 g1 = *(const floatx4*)(brow + kk + 4);
    floatx4 g2 = *(const floatx4*)(brow + kk + 8);
    floatx4 g3 = *(const floatx4*)(brow + kk + 12);
    uint4 b0 = pack8(g0, g1), b1 = pack8(g2, g3);
    __syncthreads();
    *(uint4*)(As + lr * 64 + ((c0 ^ (lr & 7)) * 8)) = a0;
    *(uint4*)(As + lr * 64 + (((c0 + 1) ^ (lr & 7)) * 8)) = a1;
    *(uint4*)(Bs + lr * 64 + ((c0 ^ (lr & 7)) * 8)) = b0;
    *(uint4*)(Bs + lr * 64 + (((c0 + 1) ^ (lr & 7)) * 8)) = b1;
    __syncthreads();
#pragma unroll
    for (int ks = 0; ks < 2; ++ks) {
      bf16x8 af = *(const bf16x8*)(As + (wave * 16 + lm) * 64 + (((ks * 4 + quad) ^ (lm & 7)) * 8));
#pragma unroll
      for (int ct = 0; ct < 4; ++ct) {
        bf16x8 bfr = *(const bf16x8*)(Bs + (ct * 16 + lm) * 64 + (((ks * 4 + quad) ^ (lm & 7)) * 8));
        acc[ct] = __builtin_amdgcn_mfma_f32_16x16x32_bf16(af, bfr, acc[ct], 0, 0, 0);
      }
    }
  }

#pragma unroll
  for (int ct = 0; ct < 4; ++ct) {
#pragma unroll
    for (int rg = 0; rg < 4; ++rg) {
      int mg = m0 + wave * 16 + quad * 4 + rg;   // C/D: row = quad*4+reg
      int ng = n0 + ct * 16 + lm;                // C/D: col = lane&15
      float v = acc[ct][rg] + bias[ng];
      if (MODE == 0) {
        ((float*)outv)[(size_t)mg * N + ng] = v;
      } else {
        int bb = mg >> 10, kp = mg & 1023;
        ((unsigned short*)outv)[((size_t)(bb * 512 + ng)) * 1024 + kp] = f2bf(v);
      }
    }
  }
}

// ---------------------------------------------------------------------------
// Kernel 2: fused mask + softmax + PV + bias copy. fp32 bias in/out, bf16 PV.
// Grid: 2048 blocks = (b,h,q-tile of 16). Block 256 threads (4 waves).
// ---------------------------------------------------------------------------
__global__ __launch_bounds__(256) void softmax_pv_kernel(const float* __restrict__ bias,
                                                         const unsigned int* __restrict__ mbits,
                                                         const unsigned short* __restrict__ vt,
                                                         float* __restrict__ bias_out,
                                                         unsigned short* __restrict__ xout) {
  __shared__ char smem[16 * 1024 * 2];   // 32 KB: bf16 p tile; later aliased as fp32 reduce buf
  __shared__ float rowinv[16];
  unsigned short* w_tile = (unsigned short*)smem;
  float* red = (float*)smem;             // 4 waves x 16 rows x 64 cols fp32 = 16 KB

  int bid = blockIdx.x;
  int qt = bid & 63, h = (bid >> 6) & 7, b = bid >> 9;
  int q0 = qt * 16;
  int t = threadIdx.x;

  // ---- pass 1: stream bias row (fp32), copy out verbatim, mask, max, exp->bf16 LDS ----
  int r = t >> 4, c = t & 15;            // 16 threads per row
  int q = q0 + r;
  size_t boff = ((size_t)((b * 8 + h) * 1024 + q)) << 10;
  const float* brow = bias + boff;
  float* brow_out = bias_out + boff;
  const unsigned int* mrow = mbits + (b * 1024 + q) * 32;

  float w[64];
  float mx = -3.4e38f;
#pragma unroll
  for (int i = 0; i < 8; ++i) {
    int k0 = c * 8 + i * 128;
    floatx4 b0 = *(const floatx4*)(brow + k0);
    floatx4 b1 = *(const floatx4*)(brow + k0 + 4);
    *(floatx4*)(brow_out + k0) = b0;         // fused bias copy (output 1), exact fp32
    *(floatx4*)(brow_out + k0 + 4) = b1;
    unsigned int bm = (mrow[k0 >> 5] >> (k0 & 31)) & 0xffu;
#pragma unroll
    for (int j = 0; j < 4; ++j) {
      float v0 = ((bm >> j) & 1u) ? b0[j] : -1e9f;
      float v1 = ((bm >> (4 + j)) & 1u) ? b1[j] : -1e9f;
      w[i * 8 + j] = v0; w[i * 8 + 4 + j] = v1;
      mx = fmaxf(mx, fmaxf(v0, v1));
    }
  }
#pragma unroll
  for (int off = 1; off < 16; off <<= 1) mx = fmaxf(mx, __shfl_xor(mx, off, 64));

  float sum = 0.f;
#pragma unroll
  for (int i = 0; i < 8; ++i) {
    union { uint4 v; unsigned short u[8]; } p;
#pragma unroll
    for (int j = 0; j < 8; ++j) {
      float e = __expf(w[i * 8 + j] - mx);
      sum += e;
      p.u[j] = f2bf(e);
    }
    int ch = c + 16 * i;                 // chunk index 0..127
    *(uint4*)(w_tile + r * 1024 + ((ch ^ (r & 7)) * 8)) = p.v;  // swizzled store
  }
#pragma unroll
  for (int off = 1; off < 16; off <<= 1) sum += __shfl_xor(sum, off, 64);
  if (c == 0) rowinv[r] = 1.0f / sum;
  __syncthreads();

  // ---- pass 2: PV via MFMA, wave w covers k in [w*256, w*256+256) ----
  int wave = t >> 6, l = t & 63, lm = l & 15, quad = l >> 4;
  floatx4 acc[4] = {{0,0,0,0},{0,0,0,0},{0,0,0,0},{0,0,0,0}};
  const unsigned short* vbase = vt + ((size_t)((b * 8 + h) * 64)) * 1024;  // [d][k] rows, bf16
#pragma unroll
  for (int s = 0; s < 8; ++s) {
    int kt = wave * 8 + s;               // k-tile of 32
    int ch = kt * 4 + quad;
    bf16x8 af = *(const bf16x8*)(w_tile + lm * 1024 + ((ch ^ (lm & 7)) * 8));  // A: p[q=lm][k]
    int kk = kt * 32 + quad * 8;
#pragma unroll
    for (int ct = 0; ct < 4; ++ct) {     // B: v[k][d=ct*16+lm]
      bf16x8 bfr = *(const bf16x8*)(vbase + (size_t)(ct * 16 + lm) * 1024 + kk);
      acc[ct] = __builtin_amdgcn_mfma_f32_16x16x32_bf16(af, bfr, acc[ct], 0, 0, 0);
    }
  }
  __syncthreads();                       // all p-tile reads done before aliasing as `red`
#pragma unroll
  for (int ct = 0; ct < 4; ++ct)
#pragma unroll
    for (int rg = 0; rg < 4; ++rg)
      red[(wave * 16 + quad * 4 + rg) * 64 + ct * 16 + lm] = acc[ct][rg];
  __syncthreads();

  int row = t >> 4, col0 = (t & 15) * 4;
  float inv = rowinv[row];
  union { ushort4 v; unsigned short u[4]; } st;
#pragma unroll
  for (int i = 0; i < 4; ++i) {
    int col = col0 + i;
    float vsum = red[(0 * 16 + row) * 64 + col] + red[(1 * 16 + row) * 64 + col] +
                 red[(2 * 16 + row) * 64 + col] + red[(3 * 16 + row) * 64 + col];
    st.u[i] = f2bf(vsum * inv);
  }
  // x layout [b][q][h][64] == row-major [4096][512] (bf16) for the output GEMM
  *(ushort4*)(xout + (((size_t)(b * 1024 + q0 + row) * 8 + h) * 64 + col0)) = st.v;
}

// ---------------------------------------------------------------------------
extern "C" void kernel_launch(void* const* d_in, const int* in_sizes, int n_in,
                              void* d_out, int out_size, void* d_ws, size_t ws_size,
                              hipStream_t stream) {
  // inputs: 0 query (unused), 1 key (unused), 2 value, 3 bias, 4 mask,
  //         5 W_v, 6 b_v, 7 W_o, 8 b_o   — all fp32 except mask (int32)
  const float* value = (const float*)d_in[2];
  const float* bias  = (const float*)d_in[3];
  const int*   mask  = (const int*)d_in[4];
  const float* W_v   = (const float*)d_in[5];
  const float* b_v   = (const float*)d_in[6];
  const float* W_o   = (const float*)d_in[7];
  const float* b_o   = (const float*)d_in[8];

  float* out = (float*)d_out;                              // [4,1024,512] fp32
  float* bias_out = out + (size_t)4 * 1024 * 512;          // bias copy region, fp32

  char* ws = (char*)d_ws;
  unsigned short* vT    = (unsigned short*)ws;             // [B*H*64][1024] bf16, 4 MB
  unsigned short* xbuf  = (unsigned short*)(ws + (4 << 20)); // [B,S,H,64] bf16, 4 MB
  unsigned int*   mbits = (unsigned int*)(ws + (8 << 20)); // 512 KB bit mask

  pack_mask_kernel<<<dim3(4 * 1024 * 1024 / 256), 256, 0, stream>>>(mask, mbits);
  gemm_nt_kernel<1><<<dim3(64, 8), 256, 0, stream>>>(value, W_v, b_v, vT, 4096, 512, 512);
  softmax_pv_kernel<<<dim3(2048), 256, 0, stream>>>(bias, mbits, vT, bias_out, xbuf);
  gemm_nt_kernel<0><<<dim3(64, 8), 256, 0, stream>>>(xbuf, W_o, b_o, out, 4096, 512, 512);
}